// Round 2
// baseline (390.024 us; speedup 1.0000x reference)
//
#include <hip/hip_runtime.h>
#include <stdint.h>

// Batched tiny MLP [B,13]->16->(30x 16->16 relu)->1, fp32 in/out, f16 MFMA.
// Transposed formulation: mfma_f32_16x16x16_f16 D layout == B layout, so each
// layer's relu'd output is the next layer's B fragment in-register.
// R14 == R13 resubmit (previous bench died to container infra, not kernel:
// no pytest/absmax ever ran; kernel audited OOB-clean and hang-free).
// R13: VALU/register-pressure attack. R12 ran at 44 cyc/SIMD/tile-layer vs the
// ~16.2 MFMA floor; VALUBusy 48% = ~10.5 VALU instr/tile-layer vs the 4 the
// relu needs. Cause: VGPR_Count=32 under launch_bounds(1024,8) (64-reg cap)
// => compiler split 32 arch + 32 AGPR and bounced MFMA results through
// v_accvgpr copies. Fix: (a) drop the x LDS staging round-trip -- each lane's
// input fragment is 4 consecutive dwords of a contiguous 832B tile, loadable
// as ONE align-4 global_load_dwordx4 straight from global (L3-resident;
// chunks tile the region => coalesced). Frees 13 prefetch VGPRs, ~24
// instrs/iter, 54KB LDS, and the staging bank conflicts. (b) fuse relu into
// the MFMA loop (1 live acc, not d[4]=16 regs). (c) T=4->8 tiles/wave with
// the freed regs: halves per-tile-layer A/bias LDS share; 2 clean sweeps.
// Live set ~54 regs => fits 64-cap in arch VGPRs, no AGPR traffic.
// Edge case: lane(col=15,g=3) k0=12 gather would read 2 dwords past x's end
// on the last tile (x is exactly page-sized: 2097152*52 = 26624*4096). That
// lane loads shifted by -3 dwords and selects v[3] as k=12, zeros for k>=13
// (A rows 13..15 are zero-padded, but garbage there must be FINITE, so we
// force 0 rather than rely on neighbor bytes).

typedef __attribute__((ext_vector_type(4))) _Float16 half4v;
typedef __attribute__((ext_vector_type(2))) _Float16 h2;
typedef __attribute__((ext_vector_type(4))) float float4v;

#define S_IN 13
#define H 16
#define NL 32            // mfma layers: 0 = input, 1..30 = hidden, 31 = output
#define TPB 1024
#define WPB 16           // waves per block
#define T 8              // 16-sample tiles per wave per iteration
#define NBLOCKS 512      // 2 blocks/CU * 256 CUs
#define STRIDE (NBLOCKS * WPB * T)   // tiles per grid sweep = 65536

// LDS dword map (weights/bias only now):
//   [0, 4096)     A-frags: 2 dwords (4 f16) per (L, lane)
//   [4096, 4608)  bias[L][m] fp32 (C-operand order)
#define LDS_DW 4608

__device__ __forceinline__ unsigned pkh(float a, float b) {
    return __builtin_bit_cast(unsigned, __builtin_amdgcn_cvt_pkrtz(a, b));
}

__device__ __forceinline__ half4v pack4h(float v0, float v1, float v2, float v3) {
    int2 p;
    p.x = (int)pkh(v0, v1);
    p.y = (int)pkh(v2, v3);
    return __builtin_bit_cast(half4v, p);
}

// cvt then packed-f16 relu: 2 cvt + 2 v_pk_max_f16
__device__ __forceinline__ half4v relu_pack4h(const float4v& d) {
    const h2 z = {(_Float16)0.f, (_Float16)0.f};
    h2 lo = __builtin_bit_cast(h2, pkh(d[0], d[1]));
    h2 hi = __builtin_bit_cast(h2, pkh(d[2], d[3]));
    lo = __builtin_elementwise_max(lo, z);
    hi = __builtin_elementwise_max(hi, z);
    int2 p;
    p.x = __builtin_bit_cast(int, lo);
    p.y = __builtin_bit_cast(int, hi);
    return __builtin_bit_cast(half4v, p);
}

// align-4 16B load (tile rows are dword- but not 16B-aligned: stride 13 dw)
__device__ __forceinline__ float4v ld4u(const float* p) {
    float4v r;
    __builtin_memcpy(&r, p, 16);
    return r;
}

__global__ __launch_bounds__(TPB, 8)
void mlp_kernel(const float* __restrict__ x,
                const float* __restrict__ W_in, const float* __restrict__ b_in,
                const float* __restrict__ W_h,  const float* __restrict__ b_h,
                const float* __restrict__ W_out,const float* __restrict__ b_out,
                float* __restrict__ out, int tiles)
{
    __shared__ unsigned lds[LDS_DW];
    const int tid = threadIdx.x;

    // ---- swizzle weights into f16 A-fragment layout in LDS (once/block) ----
    for (int s = tid; s < NL * 64; s += TPB) {
        const int L = s >> 6, ln = s & 63, m = ln & 15, gg = ln >> 4;
        float v[4];
#pragma unroll
        for (int i = 0; i < 4; ++i) {
            const int k = 4 * gg + i;
            if (L == 0)       v[i] = (k < S_IN) ? W_in[m * S_IN + k] : 0.f;
            else if (L <= 30) v[i] = W_h[(L - 1) * H * H + m * H + k];
            else              v[i] = (m == 0) ? W_out[k] : 0.f;
        }
        lds[s * 2]     = pkh(v[0], v[1]);
        lds[s * 2 + 1] = pkh(v[2], v[3]);
    }
    for (int s = tid; s < NL * H; s += TPB) {
        const int L = s >> 4, m = s & 15;
        float bv;
        if (L == 0)       bv = b_in[m];
        else if (L <= 30) bv = b_h[(L - 1) * H + m];
        else              bv = (m == 0) ? b_out[0] : 0.f;
        lds[4096 + s] = __float_as_uint(bv);
    }
    __syncthreads();

    const half4v* lA = (const half4v*)lds;             // [NL*64], 8B elems
    const float4v* lB = (const float4v*)(lds + 4096);  // [NL*4]

    const int lane = tid & 63;
    const int wv   = tid >> 6;
    const int g    = lane >> 4;
    const int col  = lane & 15;
    const bool edge = (col == 15) && (g == 3);         // lane 63: k0=12 overshoot
    const int goff = col * 13 + 4 * g - (edge ? 3 : 0);

    const int wave_id = blockIdx.x * WPB + wv;
    int tb = wave_id * T;
    if (tb >= tiles) return;

    float* op = out + (size_t)tb * 16 + lane;

    for (; tb < tiles; tb += STRIDE) {
        // ---- direct global gather: 1 dwordx4 per lane per tile ----
        const float* xp = x + (size_t)tb * 208 + goff;
        float4v v[T];
#pragma unroll
        for (int t = 0; t < T; ++t)
            v[t] = ld4u(xp + t * 208);

        half4v bf[T];
#pragma unroll
        for (int t = 0; t < T; ++t) {
            const float a0 = edge ? v[t][3] : v[t][0];
            const float a1 = edge ? 0.f : v[t][1];
            const float a2 = edge ? 0.f : v[t][2];
            const float a3 = edge ? 0.f : v[t][3];
            bf[t] = pack4h(a0, a1, a2, a3);
        }

        // ---- 31 layers, A/bias prefetched TWO ahead; bias rides in C ----
        half4v aC = lA[lane];              // layer 0
        half4v aN = lA[64 + lane];         // layer 1
        float4v cC = lB[g];
        float4v cN = lB[4 + g];
#pragma unroll
        for (int L = 0; L < NL - 1; ++L) {
            half4v aN2 = aN;
            float4v cN2 = cN;
            if (L + 2 < NL) {
                aN2 = lA[(L + 2) * 64 + lane];
                cN2 = lB[(L + 2) * 4 + g];
            }
#pragma unroll
            for (int t = 0; t < T; ++t) {
                float4v d = __builtin_amdgcn_mfma_f32_16x16x16f16(aC, bf[t], cC, 0, 0, 0);
                bf[t] = relu_pack4h(d);
            }
            aC = aN; aN = aN2;
            cC = cN; cN = cN2;
        }

        // output layer: W_out lives in row 0 only; y[n] = D[0][n]
#pragma unroll
        for (int t = 0; t < T; ++t) {
            float4v d = __builtin_amdgcn_mfma_f32_16x16x16f16(aC, bf[t], cC, 0, 0, 0);
            if (lane < 16) op[t * 16] = d[0];
        }
        op += (size_t)STRIDE * 16;
    }
}

extern "C" void kernel_launch(void* const* d_in, const int* in_sizes, int n_in,
                              void* d_out, int out_size, void* d_ws, size_t ws_size,
                              hipStream_t stream) {
    const float* x     = (const float*)d_in[0];
    const float* W_in  = (const float*)d_in[1];
    const float* b_in  = (const float*)d_in[2];
    const float* W_h   = (const float*)d_in[3];
    const float* b_h   = (const float*)d_in[4];
    const float* W_out = (const float*)d_in[5];
    const float* b_out = (const float*)d_in[6];
    float* out = (float*)d_out;

    const int tiles = out_size / 16;                       // 131072
    int blocks = (tiles + WPB * T - 1) / (WPB * T);
    if (blocks > NBLOCKS) blocks = NBLOCKS;
    mlp_kernel<<<blocks, TPB, 0, stream>>>(x, W_in, b_in, W_h, b_h, W_out, b_out,
                                           out, tiles);
}

// Round 3
// 315.563 us; speedup vs baseline: 1.2360x; 1.2360x over previous
//
#include <hip/hip_runtime.h>
#include <stdint.h>

// Batched tiny MLP [B,13]->16->(30x 16->16 relu)->1, fp32 in/out, f16 MFMA.
// Transposed formulation: mfma_f32_16x16x16_f16 D layout == B layout, so each
// layer's relu'd output is the next layer's B fragment in-register.
// R15: fix R14's catastrophic spill. R14 kept launch_bounds(1024,8) (64-reg
// unified cap) while growing the live set to ~90 regs (v[8]+bf[8]+prefetch)
// => scratch spill: FETCH 53->422MB, WRITE 8->389MB (symmetric round-trip
// signature), MfmaUtil 10%, 274us. R15 trades occupancy for registers:
// launch_bounds(512,4) -> 128-reg cap, 4 waves/SIMD (2 blocks/CU, LDS
// 2x18.4KB). Latency hiding comes from ILP (8 independent MFMA chains/wave
// x 4 waves/SIMD = 32 streams vs ~16cyc/SIMD MFMA issue), not wave count.
// Keeps R13's structural wins: no LDS x round-trip (direct coalesced
// dwordx4 gather from global, bank conflicts 1.05M->0), relu fused into the
// MFMA loop, T=8. Restores cross-sweep software prefetch: next sweep's 8
// loads issue right after current pack, in flight across the 248-MFMA chain.
// MFMA floor ~28us, memory floor ~17us; R12 (75us) lost to VALU overhead
// under the 64-reg cap. Target 40-55us.
// Edge case: lane(col=15,g=3) k0=12 gather would read 2 dwords past x's end
// on the last tile (x is exactly 2097152*52B). That lane loads shifted by -3
// dwords and selects v[3] as k=12, zeros for k>=13 (A rows 13..15 are zero,
// but garbage must be FINITE, so force 0).

typedef __attribute__((ext_vector_type(4))) _Float16 half4v;
typedef __attribute__((ext_vector_type(2))) _Float16 h2;
typedef __attribute__((ext_vector_type(4))) float float4v;

#define S_IN 13
#define H 16
#define NL 32            // mfma layers: 0 = input, 1..30 = hidden, 31 = output
#define TPB 512
#define WPB 8            // waves per block
#define T 8              // 16-sample tiles per wave per iteration
#define NBLOCKS 512      // 2 blocks/CU * 256 CUs
#define STRIDE (NBLOCKS * WPB * T)   // tiles per grid sweep = 32768

// LDS dword map (weights/bias only):
//   [0, 4096)     A-frags: 2 dwords (4 f16) per (L, lane)
//   [4096, 4608)  bias[L][m] fp32 (C-operand order)
#define LDS_DW 4608

__device__ __forceinline__ unsigned pkh(float a, float b) {
    return __builtin_bit_cast(unsigned, __builtin_amdgcn_cvt_pkrtz(a, b));
}

__device__ __forceinline__ half4v pack4h(float v0, float v1, float v2, float v3) {
    int2 p;
    p.x = (int)pkh(v0, v1);
    p.y = (int)pkh(v2, v3);
    return __builtin_bit_cast(half4v, p);
}

// cvt then packed-f16 relu: 2 cvt + 2 v_pk_max_f16
__device__ __forceinline__ half4v relu_pack4h(const float4v& d) {
    const h2 z = {(_Float16)0.f, (_Float16)0.f};
    h2 lo = __builtin_bit_cast(h2, pkh(d[0], d[1]));
    h2 hi = __builtin_bit_cast(h2, pkh(d[2], d[3]));
    lo = __builtin_elementwise_max(lo, z);
    hi = __builtin_elementwise_max(hi, z);
    int2 p;
    p.x = __builtin_bit_cast(int, lo);
    p.y = __builtin_bit_cast(int, hi);
    return __builtin_bit_cast(half4v, p);
}

// align-4 16B load (tile rows are dword- but not 16B-aligned: stride 13 dw)
__device__ __forceinline__ float4v ld4u(const float* p) {
    float4v r;
    __builtin_memcpy(&r, p, 16);
    return r;
}

__global__ __launch_bounds__(TPB, 4)
void mlp_kernel(const float* __restrict__ x,
                const float* __restrict__ W_in, const float* __restrict__ b_in,
                const float* __restrict__ W_h,  const float* __restrict__ b_h,
                const float* __restrict__ W_out,const float* __restrict__ b_out,
                float* __restrict__ out, int tiles)
{
    __shared__ unsigned lds[LDS_DW];
    const int tid = threadIdx.x;

    // ---- swizzle weights into f16 A-fragment layout in LDS (once/block) ----
    for (int s = tid; s < NL * 64; s += TPB) {
        const int L = s >> 6, ln = s & 63, m = ln & 15, gg = ln >> 4;
        float v[4];
#pragma unroll
        for (int i = 0; i < 4; ++i) {
            const int k = 4 * gg + i;
            if (L == 0)       v[i] = (k < S_IN) ? W_in[m * S_IN + k] : 0.f;
            else if (L <= 30) v[i] = W_h[(L - 1) * H * H + m * H + k];
            else              v[i] = (m == 0) ? W_out[k] : 0.f;
        }
        lds[s * 2]     = pkh(v[0], v[1]);
        lds[s * 2 + 1] = pkh(v[2], v[3]);
    }
    for (int s = tid; s < NL * H; s += TPB) {
        const int L = s >> 4, m = s & 15;
        float bv;
        if (L == 0)       bv = b_in[m];
        else if (L <= 30) bv = b_h[(L - 1) * H + m];
        else              bv = (m == 0) ? b_out[0] : 0.f;
        lds[4096 + s] = __float_as_uint(bv);
    }
    __syncthreads();

    const half4v* lA = (const half4v*)lds;             // [NL*64], 8B elems
    const float4v* lB = (const float4v*)(lds + 4096);  // [NL*4]

    const int lane = tid & 63;
    const int wv   = tid >> 6;
    const int g    = lane >> 4;
    const int col  = lane & 15;
    const bool edge = (col == 15) && (g == 3);         // lane 63: k0=12 overshoot
    const int goff = col * 13 + 4 * g - (edge ? 3 : 0);

    const int wave_id = blockIdx.x * WPB + wv;
    int tb = wave_id * T;
    if (tb >= tiles) return;

    float* op = out + (size_t)tb * 16 + lane;

    // prefetch first iteration's gathers (1 dwordx4 per lane per tile)
    const float* xp = x + (size_t)tb * 208 + goff;
    float4v v[T];
#pragma unroll
    for (int t = 0; t < T; ++t)
        v[t] = ld4u(xp + t * 208);

    for (; tb < tiles; tb += STRIDE) {
        // pack current inputs into B fragments
        half4v bf[T];
#pragma unroll
        for (int t = 0; t < T; ++t) {
            const float a0 = edge ? v[t][3] : v[t][0];
            const float a1 = edge ? 0.f : v[t][1];
            const float a2 = edge ? 0.f : v[t][2];
            const float a3 = edge ? 0.f : v[t][3];
            bf[t] = pack4h(a0, a1, a2, a3);
        }

        // issue next sweep's gathers now: in flight across the layer chain
        const int tbn = tb + STRIDE;
        if (tbn < tiles) {
            xp = x + (size_t)tbn * 208 + goff;
#pragma unroll
            for (int t = 0; t < T; ++t)
                v[t] = ld4u(xp + t * 208);
        }

        // ---- 31 layers, A/bias prefetched TWO ahead; bias rides in C ----
        half4v aC = lA[lane];              // layer 0
        half4v aN = lA[64 + lane];         // layer 1
        float4v cC = lB[g];
        float4v cN = lB[4 + g];
#pragma unroll
        for (int L = 0; L < NL - 1; ++L) {
            half4v aN2 = aN;
            float4v cN2 = cN;
            if (L + 2 < NL) {
                aN2 = lA[(L + 2) * 64 + lane];
                cN2 = lB[(L + 2) * 4 + g];
            }
#pragma unroll
            for (int t = 0; t < T; ++t) {
                float4v d = __builtin_amdgcn_mfma_f32_16x16x16f16(aC, bf[t], cC, 0, 0, 0);
                bf[t] = relu_pack4h(d);
            }
            aC = aN; aN = aN2;
            cC = cN; cN = cN2;
        }

        // output layer: W_out lives in row 0 only; y[n] = D[0][n]
#pragma unroll
        for (int t = 0; t < T; ++t) {
            float4v d = __builtin_amdgcn_mfma_f32_16x16x16f16(aC, bf[t], cC, 0, 0, 0);
            if (lane < 16) op[t * 16] = d[0];
        }
        op += (size_t)STRIDE * 16;
    }
}

extern "C" void kernel_launch(void* const* d_in, const int* in_sizes, int n_in,
                              void* d_out, int out_size, void* d_ws, size_t ws_size,
                              hipStream_t stream) {
    const float* x     = (const float*)d_in[0];
    const float* W_in  = (const float*)d_in[1];
    const float* b_in  = (const float*)d_in[2];
    const float* W_h   = (const float*)d_in[3];
    const float* b_h   = (const float*)d_in[4];
    const float* W_out = (const float*)d_in[5];
    const float* b_out = (const float*)d_in[6];
    float* out = (float*)d_out;

    const int tiles = out_size / 16;                       // 131072
    int blocks = (tiles + WPB * T - 1) / (WPB * T);
    if (blocks > NBLOCKS) blocks = NBLOCKS;
    mlp_kernel<<<blocks, TPB, 0, stream>>>(x, W_in, b_in, W_h, b_h, W_out, b_out,
                                           out, tiles);
}